// Round 3
// baseline (276.092 us; speedup 1.0000x reference)
//
#include <hip/hip_runtime.h>
#include <math.h>

#define NB 32              // batch
#define HW (1024 * 1024)   // pixels per image
#define BINS 64            // MAX_INST
#define KLBL 64            // labels per image
#define NCLS 8             // lesion classes
#define BPI 64             // blocks per image for histogram
#define TPB 256
#define TOTAL_BLOCKS (NB * BPI)

// ---------------------------------------------------------------------------
// Fused kernel.
// Phase 1 (all 2048 blocks): per-wave LDS sub-histograms of mask values,
//   2x int4 unrolled coalesced loads, then one device-scope global atomicAdd
//   per (block, bin) into hist[32][64].
// Arrival: ticket atomic (acq_rel, agent scope); the LAST block to arrive
//   proceeds to phase 2.
// Phase 2 (one block): gather sizes via label_gt (delivered as int32 pairs),
//   scatter into per-class counts, clamp/100, BCE-with-logits, mean -> out[0].
//   hist is read with agent-scope atomic loads so cross-XCD visibility of the
//   device-scope atomicAdds is guaranteed.
// ---------------------------------------------------------------------------
__global__ __launch_bounds__(TPB) void fused_kernel(const int* __restrict__ mask,
                                                    const float* __restrict__ pred,
                                                    const int* __restrict__ lg,
                                                    int* __restrict__ hist,
                                                    int* __restrict__ ticket,
                                                    float* __restrict__ out) {
    __shared__ int sh[4][BINS];
    __shared__ float cnts[NB * NCLS];
    __shared__ float wsum[4];
    __shared__ int is_last;

    const int tid = threadIdx.x;
    const int b = blockIdx.x / BPI;
    const int part = blockIdx.x % BPI;
    const int wave = tid >> 6;

    sh[tid >> 6][tid & 63] = 0;   // 256 threads cover 4*64 entries
    __syncthreads();

    // ---- Phase 1: histogram ----
    const int4* __restrict__ p = (const int4*)(mask + (size_t)b * HW);
    const int n4 = HW / 4;            // 262144 int4 per image
    const int stride = BPI * TPB;     // 16384
    // 16 int4 per thread total; unroll 2 per iteration for more MLP
    for (int i = part * TPB + tid; i < n4; i += 2 * stride) {
        int4 v0 = p[i];
        int4 v1 = p[i + stride];
        atomicAdd(&sh[wave][v0.x & 63], 1);
        atomicAdd(&sh[wave][v0.y & 63], 1);
        atomicAdd(&sh[wave][v0.z & 63], 1);
        atomicAdd(&sh[wave][v0.w & 63], 1);
        atomicAdd(&sh[wave][v1.x & 63], 1);
        atomicAdd(&sh[wave][v1.y & 63], 1);
        atomicAdd(&sh[wave][v1.z & 63], 1);
        atomicAdd(&sh[wave][v1.w & 63], 1);
    }
    __syncthreads();

    if (tid < BINS) {
        int s = sh[0][tid] + sh[1][tid] + sh[2][tid] + sh[3][tid];
        atomicAdd(&hist[b * BINS + tid], s);   // device scope by default
    }
    __syncthreads();   // drains the global atomics (full waitcnt before barrier)

    // ---- Arrival ----
    if (tid == 0) {
        int old = __hip_atomic_fetch_add(ticket, 1, __ATOMIC_ACQ_REL,
                                         __HIP_MEMORY_SCOPE_AGENT);
        is_last = (old == TOTAL_BLOCKS - 1);
    }
    __syncthreads();
    if (!is_last) return;

    // ---- Phase 2: finalize (last block only) ----
    cnts[tid] = 0.0f;
    __syncthreads();

    for (int e = tid; e < NB * KLBL; e += TPB) {
        int inst  = lg[e * 2 + 0];
        int label = lg[e * 2 + 1];
        if (label > 0 && label <= NCLS) {
            int hv = __hip_atomic_load(&hist[(e >> 6) * BINS + (inst & 63)],
                                       __ATOMIC_RELAXED, __HIP_MEMORY_SCOPE_AGENT);
            atomicAdd(&cnts[(e >> 6) * NCLS + (label - 1)], (float)hv);
        }
    }
    __syncthreads();

    float x = pred[tid];
    float t = fminf(cnts[tid] * (1.0f / 100.0f), 1.0f);
    float l = fmaxf(x, 0.0f) - x * t + log1pf(expf(-fabsf(x)));

    for (int off = 32; off > 0; off >>= 1)
        l += __shfl_down(l, off, 64);
    if ((tid & 63) == 0) wsum[tid >> 6] = l;
    __syncthreads();
    if (tid == 0)
        out[0] = (wsum[0] + wsum[1] + wsum[2] + wsum[3]) * (1.0f / (NB * NCLS));
}

extern "C" void kernel_launch(void* const* d_in, const int* in_sizes, int n_in,
                              void* d_out, int out_size, void* d_ws, size_t ws_size,
                              hipStream_t stream) {
    const float* pred = (const float*)d_in[0];    // [32, 8] fp32
    const int*   mask = (const int*)d_in[1];      // [32, 1024, 1024] int32
    const int*   lg   = (const int*)d_in[2];      // [32, 64, 2] delivered as int32
    float* out = (float*)d_out;
    int* hist = (int*)d_ws;                       // [32][64] int32 = 8 KB
    int* ticket = hist + NB * BINS;               // 1 int arrival counter

    hipMemsetAsync(d_ws, 0, (NB * BINS + 1) * sizeof(int), stream);
    fused_kernel<<<TOTAL_BLOCKS, TPB, 0, stream>>>(mask, pred, lg, hist, ticket, out);
}

// Round 4
// 210.086 us; speedup vs baseline: 1.3142x; 1.3142x over previous
//
#include <hip/hip_runtime.h>
#include <math.h>

#define NB 32              // batch
#define HW (1024 * 1024)   // pixels per image
#define BINS 64            // MAX_INST
#define KLBL 64            // labels per image
#define NCLS 8             // lesion classes
#define BPI 64             // blocks per image for histogram
#define TPB 256
#define PH_STRIDE 68       // 64 + 4 pad: keeps 16B alignment, rotates banks

// ---------------------------------------------------------------------------
// Pair-key histogram. Two adjacent 6-bit pixel values -> one LDS atomicAdd
// into a per-block 64x64 pair-histogram (halves serialized RMW lane-incs,
// which round-2/3 counters show are the bottleneck, ~1 lane-inc/cyc/CU).
// Fold phase recovers exact per-bin counts: row sum -> high pixel's bin,
// col sum -> low pixel's bin, all non-atomic LDS reads.
// ---------------------------------------------------------------------------
__global__ __launch_bounds__(TPB) void hist_kernel(const int* __restrict__ mask,
                                                   int* __restrict__ hist) {
    __shared__ __align__(16) int ph[BINS][PH_STRIDE];  // [high a][low b], 17408 B
    __shared__ int rowp[BINS][4];                      // high-bin partials per quarter
    __shared__ int colp[BINS][4];                      // low-bin partials per wave
    const int tid = threadIdx.x;
    const int b = blockIdx.x / BPI;
    const int part = blockIdx.x % BPI;

    for (int i = tid; i < BINS * PH_STRIDE; i += TPB) ((int*)ph)[i] = 0;
    ((int*)rowp)[tid] = 0;   // 64*4 = 256 ints
    ((int*)colp)[tid] = 0;
    __syncthreads();

    // ---- accumulate: 16 int4 per lane, 2 pair-keys per int4 ----
    const int* pm = mask + (size_t)b * HW;
    const int stride = BPI * TPB;            // 16384 int4
    const int base = part * TPB + tid;
    #pragma unroll 4
    for (int k = 0; k < 16; ++k) {
        int4 v = ((const int4*)pm)[base + k * stride];
        atomicAdd(&((int*)ph)[(v.x & 63) * PH_STRIDE + (v.y & 63)], 1);
        atomicAdd(&((int*)ph)[(v.z & 63) * PH_STRIDE + (v.w & 63)], 1);
    }
    __syncthreads();

    // ---- fold: row sums (high bin a) — thread t: a = t>>2, quarter q = t&3 ----
    {
        int a = tid >> 2, q = tid & 3;
        const int4* r = (const int4*)&ph[a][q * 16];   // 68a+16q ≡ 0 mod 4 -> 16B aligned
        int4 s0 = r[0], s1 = r[1], s2 = r[2], s3 = r[3];
        rowp[a][q] = s0.x + s0.y + s0.z + s0.w + s1.x + s1.y + s1.z + s1.w
                   + s2.x + s2.y + s2.z + s2.w + s3.x + s3.y + s3.z + s3.w;
    }
    // ---- fold: col sums (low bin bb) — thread t: bb = t&63, 16 a's per wave ----
    {
        int bb = tid & 63, pq = tid >> 6;
        int s = 0;
        #pragma unroll
        for (int j = 0; j < 16; ++j) s += ph[pq * 16 + j][bb];  // banks: (4j+bb)%32, 2-way
        colp[bb][pq] = s;
    }
    __syncthreads();

    if (tid < BINS) {
        int t = rowp[tid][0] + rowp[tid][1] + rowp[tid][2] + rowp[tid][3]
              + colp[tid][0] + colp[tid][1] + colp[tid][2] + colp[tid][3];
        atomicAdd(&hist[b * BINS + tid], t);
    }
}

// ---------------------------------------------------------------------------
// Finalize (unchanged known-good): gather sizes via label_gt (int32 pairs),
// scatter into per-class counts, clamp/100, BCE-with-logits, mean -> out[0].
// ---------------------------------------------------------------------------
__global__ __launch_bounds__(TPB) void finalize_kernel(const float* __restrict__ pred,
                                                       const int* __restrict__ lg,
                                                       const int* __restrict__ hist,
                                                       float* __restrict__ out) {
    __shared__ float cnts[NB * NCLS];
    __shared__ float wsum[4];
    const int tid = threadIdx.x;

    cnts[tid] = 0.0f;
    __syncthreads();

    for (int e = tid; e < NB * KLBL; e += TPB) {
        int inst  = lg[e * 2 + 0];
        int label = lg[e * 2 + 1];
        if (label > 0 && label <= NCLS) {
            float sz = (float)hist[(e >> 6) * BINS + (inst & 63)];
            atomicAdd(&cnts[(e >> 6) * NCLS + (label - 1)], sz);
        }
    }
    __syncthreads();

    float x = pred[tid];
    float t = fminf(cnts[tid] * (1.0f / 100.0f), 1.0f);
    float l = fmaxf(x, 0.0f) - x * t + log1pf(expf(-fabsf(x)));

    for (int off = 32; off > 0; off >>= 1)
        l += __shfl_down(l, off, 64);
    if ((tid & 63) == 0) wsum[tid >> 6] = l;
    __syncthreads();
    if (tid == 0)
        out[0] = (wsum[0] + wsum[1] + wsum[2] + wsum[3]) * (1.0f / (NB * NCLS));
}

extern "C" void kernel_launch(void* const* d_in, const int* in_sizes, int n_in,
                              void* d_out, int out_size, void* d_ws, size_t ws_size,
                              hipStream_t stream) {
    const float* pred = (const float*)d_in[0];    // [32, 8] fp32
    const int*   mask = (const int*)d_in[1];      // [32, 1024, 1024] int32
    const int*   lg   = (const int*)d_in[2];      // [32, 64, 2] delivered as int32
    float* out = (float*)d_out;
    int* hist = (int*)d_ws;                       // [32][64] int32 = 8 KB

    hipMemsetAsync(hist, 0, NB * BINS * sizeof(int), stream);
    hist_kernel<<<NB * BPI, TPB, 0, stream>>>(mask, hist);
    finalize_kernel<<<1, TPB, 0, stream>>>(pred, lg, hist, out);
}

// Round 5
// 204.647 us; speedup vs baseline: 1.3491x; 1.0266x over previous
//
#include <hip/hip_runtime.h>
#include <math.h>

#define NB 32              // batch
#define HW (1024 * 1024)   // pixels per image
#define BINS 64            // MAX_INST
#define KLBL 64            // labels per image
#define NCLS 8             // lesion classes
#define BPI 64             // blocks per image for histogram
#define TPB 256
#define CHUNK4 4096        // int4 per block chunk (64 KB contiguous)

// ---------------------------------------------------------------------------
// Histogram, round-5 structure:
//  - Each block owns a CONTIGUOUS 64 KB chunk of one image (4 KB-spaced wave
//    requests walking sequentially -> dense DRAM row locality, copy-like).
//  - Loads batched 8x int4 into registers BEFORE any LDS traffic (explicit
//    MLP; compiler can keep 8 dwordx4 in flight per wave).
//  - Simple per-wave 64-bin LDS sub-histograms (atomics proven non-limiting
//    in rounds 2-4; pair-key fold reverted as neutral complexity).
// ---------------------------------------------------------------------------
__global__ __launch_bounds__(TPB) void hist_kernel(const int* __restrict__ mask,
                                                   int* __restrict__ hist) {
    __shared__ int sh[4][BINS];
    const int tid = threadIdx.x;
    const int b = blockIdx.x / BPI;
    const int part = blockIdx.x % BPI;
    const int wave = tid >> 6;

    sh[tid >> 6][tid & 63] = 0;   // 256 threads cover 4*64
    __syncthreads();

    const int4* __restrict__ p4 =
        (const int4*)(mask + (size_t)b * HW) + (size_t)part * CHUNK4;

    #pragma unroll
    for (int h = 0; h < 2; ++h) {
        int4 v[8];
        #pragma unroll
        for (int k = 0; k < 8; ++k)
            v[k] = p4[(h * 8 + k) * TPB + tid];   // wave req k: 4 KB apart, dense
        #pragma unroll
        for (int k = 0; k < 8; ++k) {
            atomicAdd(&sh[wave][v[k].x & 63], 1);
            atomicAdd(&sh[wave][v[k].y & 63], 1);
            atomicAdd(&sh[wave][v[k].z & 63], 1);
            atomicAdd(&sh[wave][v[k].w & 63], 1);
        }
    }
    __syncthreads();

    if (tid < BINS) {
        int s = sh[0][tid] + sh[1][tid] + sh[2][tid] + sh[3][tid];
        atomicAdd(&hist[b * BINS + tid], s);
    }
}

// ---------------------------------------------------------------------------
// Finalize (unchanged known-good): gather sizes via label_gt (int32 pairs),
// scatter into per-class counts, clamp/100, BCE-with-logits, mean -> out[0].
// ---------------------------------------------------------------------------
__global__ __launch_bounds__(TPB) void finalize_kernel(const float* __restrict__ pred,
                                                       const int* __restrict__ lg,
                                                       const int* __restrict__ hist,
                                                       float* __restrict__ out) {
    __shared__ float cnts[NB * NCLS];
    __shared__ float wsum[4];
    const int tid = threadIdx.x;

    cnts[tid] = 0.0f;
    __syncthreads();

    for (int e = tid; e < NB * KLBL; e += TPB) {
        int inst  = lg[e * 2 + 0];
        int label = lg[e * 2 + 1];
        if (label > 0 && label <= NCLS) {
            float sz = (float)hist[(e >> 6) * BINS + (inst & 63)];
            atomicAdd(&cnts[(e >> 6) * NCLS + (label - 1)], sz);
        }
    }
    __syncthreads();

    float x = pred[tid];
    float t = fminf(cnts[tid] * (1.0f / 100.0f), 1.0f);
    float l = fmaxf(x, 0.0f) - x * t + log1pf(expf(-fabsf(x)));

    for (int off = 32; off > 0; off >>= 1)
        l += __shfl_down(l, off, 64);
    if ((tid & 63) == 0) wsum[tid >> 6] = l;
    __syncthreads();
    if (tid == 0)
        out[0] = (wsum[0] + wsum[1] + wsum[2] + wsum[3]) * (1.0f / (NB * NCLS));
}

extern "C" void kernel_launch(void* const* d_in, const int* in_sizes, int n_in,
                              void* d_out, int out_size, void* d_ws, size_t ws_size,
                              hipStream_t stream) {
    const float* pred = (const float*)d_in[0];    // [32, 8] fp32
    const int*   mask = (const int*)d_in[1];      // [32, 1024, 1024] int32
    const int*   lg   = (const int*)d_in[2];      // [32, 64, 2] delivered as int32
    float* out = (float*)d_out;
    int* hist = (int*)d_ws;                       // [32][64] int32 = 8 KB

    hipMemsetAsync(hist, 0, NB * BINS * sizeof(int), stream);
    hist_kernel<<<NB * BPI, TPB, 0, stream>>>(mask, hist);
    finalize_kernel<<<1, TPB, 0, stream>>>(pred, lg, hist, out);
}